// Round 1
// 537.381 us; speedup vs baseline: 1.0010x; 1.0010x over previous
//
#include <hip/hip_runtime.h>
#include <math.h>

#define HH 7
#define WW 7
#define CC 512
#define HF 64
#define WF 256
#define NS 49            // HH*WW
#define CHUNK 128        // channels per tile pass
#define ROWS4 (CC / 4)   // float4 elements per spatial row of transposed feats
#define NE4 ((CHUNK * NS) / 4)   // 1568 float4 outputs per chunk

typedef float floatv4 __attribute__((ext_vector_type(4)));  // native vec for NT store

// Transpose feats (C, HF*WF) -> ws (HF*WF, C) so channel gathers coalesce.
__global__ __launch_bounds__(256) void transpose_feats(const float* __restrict__ in,
                                                       float* __restrict__ out) {
    __shared__ float tile[32][33];
    const int P = HF * WF;  // 16384
    int p  = blockIdx.x * 32 + threadIdx.x;  // spatial index
    int cb = blockIdx.y * 32;                // channel base
#pragma unroll
    for (int r = 0; r < 32; r += 8)
        tile[threadIdx.y + r][threadIdx.x] = in[(size_t)(cb + threadIdx.y + r) * P + p];
    __syncthreads();
    int c  = cb + threadIdx.x;
    int pb = blockIdx.x * 32;
#pragma unroll
    for (int r = 0; r < 32; r += 8)
        out[(size_t)(pb + threadIdx.y + r) * CC + c] = tile[threadIdx.x][threadIdx.y + r];
}

__device__ __forceinline__ void box_setup(int s, int b,
                                          const float* __restrict__ boxes,
                                          const int* __restrict__ ih_p,
                                          const int* __restrict__ iw_p,
                                          int4* o_out, float4* w_out) {
    int i = s / WW;
    int j = s - i * WW;
    float IW1 = (float)(iw_p[0] - 1);
    float IH1 = (float)(ih_p[0] - 1);
    float xc = boxes[b * 4 + 0];
    float yc = boxes[b * 4 + 1];
    float bw = boxes[b * 4 + 2];
    float bh = boxes[b * 4 + 3];
    float inv_w = 1.0f / IW1;
    float inv_h = 1.0f / IH1;
    float tx = (float)(j - 3) * (1.0f / 3.0f);   // linspace(-1,1,7)
    float ty = (float)(i - 3) * (1.0f / 3.0f);
    float gx = (2.0f * xc - IW1) * inv_w + (bw * inv_w) * tx;
    float gy = (2.0f * yc - IH1) * inv_h + (bh * inv_h) * ty;
    float px = (gx + 1.0f) * 0.5f * (float)(WF - 1);
    float py = (gy + 1.0f) * 0.5f * (float)(HF - 1);

    float x0f = floorf(px), y0f = floorf(py);
    float wx1 = px - x0f, wx0 = 1.0f - wx1;
    float wy1 = py - y0f, wy0 = 1.0f - wy1;
    float x1f = x0f + 1.0f, y1f = y0f + 1.0f;

    bool vx0 = (x0f >= 0.0f) && (x0f <= (float)(WF - 1));
    bool vx1 = (x1f >= 0.0f) && (x1f <= (float)(WF - 1));
    bool vy0 = (y0f >= 0.0f) && (y0f <= (float)(HF - 1));
    bool vy1 = (y1f >= 0.0f) && (y1f <= (float)(HF - 1));

    int xi0 = (int)fminf(fmaxf(x0f, 0.0f), (float)(WF - 1));
    int xi1 = (int)fminf(fmaxf(x1f, 0.0f), (float)(WF - 1));
    int yi0 = (int)fminf(fmaxf(y0f, 0.0f), (float)(HF - 1));
    int yi1 = (int)fminf(fmaxf(y1f, 0.0f), (float)(HF - 1));

    int4 o;
    o.x = yi0 * WF + xi0;
    o.y = yi0 * WF + xi1;
    o.z = yi1 * WF + xi0;
    o.w = yi1 * WF + xi1;
    float4 w4;
    w4.x = wx0 * wy0 * ((vx0 && vy0) ? 1.0f : 0.0f);
    w4.y = wx1 * wy0 * ((vx1 && vy0) ? 1.0f : 0.0f);
    w4.z = wx0 * wy1 * ((vx0 && vy1) ? 1.0f : 0.0f);
    w4.w = wx1 * wy1 * ((vx1 && vy1) ? 1.0f : 0.0f);
    *o_out = o;
    *w_out = w4;
}

// One block per box. src is transposed feats: (HF*WF, CC), channel-contiguous.
// LDS layout: addr(s,c) = c*64 + (sigma(s) ^ (c>>2)),  sigma(s) = (s>>2)|((s&3)<<4).
//   compute phase (fixed s, lane g=c>>2): bank = (sigma^g)&31 -> all 32 banks/half-wave: free
//   write   phase (s steps 4 per lane):  sigma steps 1        -> bank steps 1:        free
__global__ __launch_bounds__(256) void roi_pool_v3(const float* __restrict__ src,
                                                   const float* __restrict__ boxes,
                                                   const int* __restrict__ ih_p,
                                                   const int* __restrict__ iw_p,
                                                   float* __restrict__ out) {
    __shared__ int4   s_off[NS];   // float4-row base: cell*ROWS4
    __shared__ float4 s_wt[NS];
    __shared__ float  tile[CHUNK * 64];  // 32 KB, XOR-swizzled

    const int b   = blockIdx.x;
    const int tid = threadIdx.x;
    const int g   = tid & 31;   // float4 channel-group within 128-chunk (c>>2)
    const int h   = tid >> 5;   // sample phase 0..7

    if (tid < NS) {
        int4 o; float4 w4;
        box_setup(tid, b, boxes, ih_p, iw_p, &o, &w4);
        o.x *= ROWS4; o.y *= ROWS4; o.z *= ROWS4; o.w *= ROWS4;
        s_off[tid] = o;
        s_wt[tid]  = w4;
    }
    __syncthreads();

    // Hoist per-sample constants into registers (static unroll -> stays in VGPRs).
    int4   o_r[7];
    float4 w_r[7];
    int    sig_r[7];
#pragma unroll
    for (int it = 0; it < 7; ++it) {
        int s = h + (it << 3);
        if (s < NS) {
            o_r[it]   = s_off[s];
            w_r[it]   = s_wt[s];
            sig_r[it] = (s >> 2) | ((s & 3) << 4);
        }
    }

    const size_t outbase = (size_t)b * (CC * NS);
    const float4* src4   = (const float4*)src;

    for (int c0 = 0; c0 < CC; c0 += CHUNK) {
        const int cb4 = c0 >> 2;
        // ---- compute phase: half-wave = one sample, lane = 4-channel group ----
#pragma unroll
        for (int it = 0; it < 7; ++it) {
            int s = h + (it << 3);
            if (s < NS) {
                int4   o = o_r[it];
                float4 w = w_r[it];
                float4 a  = src4[o.x + cb4 + g];
                float4 bb = src4[o.y + cb4 + g];
                float4 c  = src4[o.z + cb4 + g];
                float4 d  = src4[o.w + cb4 + g];
                int base = g << 8;              // c_local=4g -> c*64
                int sw   = sig_r[it] ^ g;
                tile[base +       sw] = a.x * w.x + bb.x * w.y + c.x * w.z + d.x * w.w;
                tile[base +  64 + sw] = a.y * w.x + bb.y * w.y + c.y * w.z + d.y * w.w;
                tile[base + 128 + sw] = a.z * w.x + bb.z * w.y + c.z * w.z + d.z * w.w;
                tile[base + 192 + sw] = a.w * w.x + bb.w * w.y + c.w * w.z + d.w * w.w;
            }
        }
        __syncthreads();
        // ---- write phase: lane = output order (coalesced float4 NT stores) ----
        float* outc = out + outbase + (size_t)c0 * NS;
        for (int k4 = tid; k4 < NE4; k4 += 256) {
            int e = k4 << 2;
            int c = e / NS;          // compiler magic-mul
            int s = e - c * NS;
            floatv4 v;
            v.x = tile[(c << 6) + (((s >> 2) | ((s & 3) << 4)) ^ (c >> 2))];
            if (++s == NS) { s = 0; ++c; }
            v.y = tile[(c << 6) + (((s >> 2) | ((s & 3) << 4)) ^ (c >> 2))];
            if (++s == NS) { s = 0; ++c; }
            v.z = tile[(c << 6) + (((s >> 2) | ((s & 3) << 4)) ^ (c >> 2))];
            if (++s == NS) { s = 0; ++c; }
            v.w = tile[(c << 6) + (((s >> 2) | ((s & 3) << 4)) ^ (c >> 2))];
            __builtin_nontemporal_store(v, (floatv4*)outc + k4);
        }
        __syncthreads();
    }
}

// Fallback (ws too small for transpose): original scalar path on raw feats.
__global__ __launch_bounds__(256) void roi_pool_fb(const float* __restrict__ src,
                                                   const float* __restrict__ boxes,
                                                   const int* __restrict__ ih_p,
                                                   const int* __restrict__ iw_p,
                                                   float* __restrict__ out) {
    __shared__ int4   s_off[NS];
    __shared__ float4 s_wt[NS];
    __shared__ float  tile[NS * 257];

    const int b   = blockIdx.x;
    const int tid = threadIdx.x;

    if (tid < NS) {
        int4 o; float4 w4;
        box_setup(tid, b, boxes, ih_p, iw_p, &o, &w4);
        s_off[tid] = o;
        s_wt[tid]  = w4;
    }
    __syncthreads();

    const size_t outbase = (size_t)b * (CC * NS);
    for (int c0 = 0; c0 < CC; c0 += 256) {
        const int cterm = (c0 + tid) * (HF * WF);
        for (int s = 0; s < NS; ++s) {
            int4   o = s_off[s];
            float4 w = s_wt[s];
            float v = src[o.x + cterm] * w.x + src[o.y + cterm] * w.y +
                      src[o.z + cterm] * w.z + src[o.w + cterm] * w.w;
            tile[s * 257 + tid] = v;
        }
        __syncthreads();
        const size_t ob = outbase + (size_t)c0 * NS;
        for (int k = tid; k < 256 * NS; k += 256) {
            int cl = k / NS;
            int s  = k - cl * NS;
            out[ob + k] = tile[s * 257 + cl];
        }
        __syncthreads();
    }
}

extern "C" void kernel_launch(void* const* d_in, const int* in_sizes, int n_in,
                              void* d_out, int out_size, void* d_ws, size_t ws_size,
                              hipStream_t stream) {
    const float* feats = (const float*)d_in[0];
    const float* boxes = (const float*)d_in[1];
    const int*   ih    = (const int*)d_in[2];
    const int*   iw    = (const int*)d_in[3];
    float*       out   = (float*)d_out;
    const int B = in_sizes[1] / 4;

    const size_t need = (size_t)CC * HF * WF * sizeof(float);  // 32 MiB
    if (ws_size >= need) {
        float* tf = (float*)d_ws;
        dim3 tb(32, 8);
        dim3 tg((HF * WF) / 32, CC / 32);
        transpose_feats<<<tg, tb, 0, stream>>>(feats, tf);
        roi_pool_v3<<<B, 256, 0, stream>>>(tf, boxes, ih, iw, out);
    } else {
        roi_pool_fb<<<B, 256, 0, stream>>>(feats, boxes, ih, iw, out);
    }
}

// Round 2
// 473.489 us; speedup vs baseline: 1.1361x; 1.1349x over previous
//
#include <hip/hip_runtime.h>
#include <math.h>

#define HH 7
#define WW 7
#define CC 512
#define HF 64
#define WF 256
#define NS 49            // HH*WW
#define CHUNK 128        // channels per tile pass
#define ROWS4 (CC / 4)   // float4 elements per spatial row of transposed feats
#define NE4 ((CHUNK * NS) / 4)   // 1568 float4 outputs per chunk
#define NBINS 2048       // 32 y-bands x 64 x-bins (serpentine)

typedef float floatv4 __attribute__((ext_vector_type(4)));  // native vec for NT store

// Transpose feats (C, HF*WF) -> ws (HF*WF, C) so channel gathers coalesce.
__global__ __launch_bounds__(256) void transpose_feats(const float* __restrict__ in,
                                                       float* __restrict__ out) {
    __shared__ float tile[32][33];
    const int P = HF * WF;  // 16384
    int p  = blockIdx.x * 32 + threadIdx.x;  // spatial index
    int cb = blockIdx.y * 32;                // channel base
#pragma unroll
    for (int r = 0; r < 32; r += 8)
        tile[threadIdx.y + r][threadIdx.x] = in[(size_t)(cb + threadIdx.y + r) * P + p];
    __syncthreads();
    int c  = cb + threadIdx.x;
    int pb = blockIdx.x * 32;
#pragma unroll
    for (int r = 0; r < 32; r += 8)
        out[(size_t)(pb + threadIdx.y + r) * CC + c] = tile[threadIdx.x][threadIdx.y + r];
}

// Spatial bin key: serpentine over (y-band, x-bin) so sorted order sweeps the
// feature map with x-locality inside each band.
__device__ __forceinline__ int box_key(const float* __restrict__ boxes, int b,
                                       float sy, float sx) {
    float xc = boxes[b * 4 + 0];
    float yc = boxes[b * 4 + 1];
    int yb = (int)(yc * sy);
    int xb = (int)(xc * sx);
    yb = min(max(yb, 0), 31);
    xb = min(max(xb, 0), 63);
    if (yb & 1) xb = 63 - xb;          // serpentine
    return (yb << 6) | xb;
}

// Single-block counting sort of boxes by spatial bin -> perm (rank -> box id).
__global__ __launch_bounds__(256) void sort_boxes(const float* __restrict__ boxes,
                                                  const int* __restrict__ ih_p,
                                                  const int* __restrict__ iw_p,
                                                  int B, int* __restrict__ perm) {
    __shared__ int hist[NBINS];
    __shared__ int part[256];
    const int tid = threadIdx.x;
    const float sy = 32.0f / (float)ih_p[0];
    const float sx = 64.0f / (float)iw_p[0];

    for (int i = tid; i < NBINS; i += 256) hist[i] = 0;
    __syncthreads();
    for (int b = tid; b < B; b += 256)
        atomicAdd(&hist[box_key(boxes, b, sy, sx)], 1);
    __syncthreads();
    // exclusive prefix sum over NBINS (8 bins/thread + serial scan of 256 partials)
    const int base = tid * (NBINS / 256);
    int s = 0;
#pragma unroll
    for (int i = 0; i < NBINS / 256; ++i) { int v = hist[base + i]; hist[base + i] = s; s += v; }
    part[tid] = s;
    __syncthreads();
    if (tid == 0) {
        int acc = 0;
        for (int t = 0; t < 256; ++t) { int v = part[t]; part[t] = acc; acc += v; }
    }
    __syncthreads();
    const int off = part[tid];
#pragma unroll
    for (int i = 0; i < NBINS / 256; ++i) hist[base + i] += off;
    __syncthreads();
    for (int b = tid; b < B; b += 256) {
        int pos = atomicAdd(&hist[box_key(boxes, b, sy, sx)], 1);
        perm[pos] = b;
    }
}

__device__ __forceinline__ void box_setup(int s, int b,
                                          const float* __restrict__ boxes,
                                          const int* __restrict__ ih_p,
                                          const int* __restrict__ iw_p,
                                          int4* o_out, float4* w_out) {
    int i = s / WW;
    int j = s - i * WW;
    float IW1 = (float)(iw_p[0] - 1);
    float IH1 = (float)(ih_p[0] - 1);
    float xc = boxes[b * 4 + 0];
    float yc = boxes[b * 4 + 1];
    float bw = boxes[b * 4 + 2];
    float bh = boxes[b * 4 + 3];
    float inv_w = 1.0f / IW1;
    float inv_h = 1.0f / IH1;
    float tx = (float)(j - 3) * (1.0f / 3.0f);   // linspace(-1,1,7)
    float ty = (float)(i - 3) * (1.0f / 3.0f);
    float gx = (2.0f * xc - IW1) * inv_w + (bw * inv_w) * tx;
    float gy = (2.0f * yc - IH1) * inv_h + (bh * inv_h) * ty;
    float px = (gx + 1.0f) * 0.5f * (float)(WF - 1);
    float py = (gy + 1.0f) * 0.5f * (float)(HF - 1);

    float x0f = floorf(px), y0f = floorf(py);
    float wx1 = px - x0f, wx0 = 1.0f - wx1;
    float wy1 = py - y0f, wy0 = 1.0f - wy1;
    float x1f = x0f + 1.0f, y1f = y0f + 1.0f;

    bool vx0 = (x0f >= 0.0f) && (x0f <= (float)(WF - 1));
    bool vx1 = (x1f >= 0.0f) && (x1f <= (float)(WF - 1));
    bool vy0 = (y0f >= 0.0f) && (y0f <= (float)(HF - 1));
    bool vy1 = (y1f >= 0.0f) && (y1f <= (float)(HF - 1));

    int xi0 = (int)fminf(fmaxf(x0f, 0.0f), (float)(WF - 1));
    int xi1 = (int)fminf(fmaxf(x1f, 0.0f), (float)(WF - 1));
    int yi0 = (int)fminf(fmaxf(y0f, 0.0f), (float)(HF - 1));
    int yi1 = (int)fminf(fmaxf(y1f, 0.0f), (float)(HF - 1));

    int4 o;
    o.x = yi0 * WF + xi0;
    o.y = yi0 * WF + xi1;
    o.z = yi1 * WF + xi0;
    o.w = yi1 * WF + xi1;
    float4 w4;
    w4.x = wx0 * wy0 * ((vx0 && vy0) ? 1.0f : 0.0f);
    w4.y = wx1 * wy0 * ((vx1 && vy0) ? 1.0f : 0.0f);
    w4.z = wx0 * wy1 * ((vx0 && vy1) ? 1.0f : 0.0f);
    w4.w = wx1 * wy1 * ((vx1 && vy1) ? 1.0f : 0.0f);
    *o_out = o;
    *w_out = w4;
}

// One block per box (via perm + bijective XCD chunking). src is transposed
// feats: (HF*WF, CC), channel-contiguous.
// LDS layout: addr(s,c) = c*64 + (sigma(s) ^ (c>>2)),  sigma(s) = (s>>2)|((s&3)<<4).
__global__ __launch_bounds__(256) void roi_pool_v4(const float* __restrict__ src,
                                                   const float* __restrict__ boxes,
                                                   const int* __restrict__ ih_p,
                                                   const int* __restrict__ iw_p,
                                                   const int* __restrict__ perm,
                                                   float* __restrict__ out) {
    __shared__ int4   s_off[NS];   // float4-row base: cell*ROWS4
    __shared__ float4 s_wt[NS];
    __shared__ float  tile[CHUNK * 64];  // 32 KB, XOR-swizzled

    // Bijective XCD chunking: XCD k (blocks bid%8==k) processes contiguous
    // sorted ranks -> concurrent blocks on one XCD share a spatial band.
    const int nwg  = gridDim.x;
    const int bid  = blockIdx.x;
    const int q    = nwg >> 3, r = nwg & 7;
    const int xcd  = bid & 7, slot = bid >> 3;
    const int rank = xcd * q + min(xcd, r) + slot;
    const int b    = perm[rank];

    const int tid = threadIdx.x;
    const int g   = tid & 31;   // float4 channel-group within 128-chunk (c>>2)
    const int h   = tid >> 5;   // sample phase 0..7

    if (tid < NS) {
        int4 o; float4 w4;
        box_setup(tid, b, boxes, ih_p, iw_p, &o, &w4);
        o.x *= ROWS4; o.y *= ROWS4; o.z *= ROWS4; o.w *= ROWS4;
        s_off[tid] = o;
        s_wt[tid]  = w4;
    }
    __syncthreads();

    // Hoist per-sample constants into registers (static unroll -> stays in VGPRs).
    int4   o_r[7];
    float4 w_r[7];
    int    sig_r[7];
#pragma unroll
    for (int it = 0; it < 7; ++it) {
        int s = h + (it << 3);
        if (s < NS) {
            o_r[it]   = s_off[s];
            w_r[it]   = s_wt[s];
            sig_r[it] = (s >> 2) | ((s & 3) << 4);
        }
    }

    const size_t outbase = (size_t)b * (CC * NS);
    const float4* src4   = (const float4*)src;

    for (int c0 = 0; c0 < CC; c0 += CHUNK) {
        const int cb4 = c0 >> 2;
        // ---- compute phase: half-wave = one sample, lane = 4-channel group ----
#pragma unroll
        for (int it = 0; it < 7; ++it) {
            int s = h + (it << 3);
            if (s < NS) {
                int4   o = o_r[it];
                float4 w = w_r[it];
                float4 a  = src4[o.x + cb4 + g];
                float4 bb = src4[o.y + cb4 + g];
                float4 c  = src4[o.z + cb4 + g];
                float4 d  = src4[o.w + cb4 + g];
                int base = g << 8;              // c_local=4g -> c*64
                int sw   = sig_r[it] ^ g;
                tile[base +       sw] = a.x * w.x + bb.x * w.y + c.x * w.z + d.x * w.w;
                tile[base +  64 + sw] = a.y * w.x + bb.y * w.y + c.y * w.z + d.y * w.w;
                tile[base + 128 + sw] = a.z * w.x + bb.z * w.y + c.z * w.z + d.z * w.w;
                tile[base + 192 + sw] = a.w * w.x + bb.w * w.y + c.w * w.z + d.w * w.w;
            }
        }
        __syncthreads();
        // ---- write phase: lane = output order (coalesced float4 NT stores) ----
        float* outc = out + outbase + (size_t)c0 * NS;
        for (int k4 = tid; k4 < NE4; k4 += 256) {
            int e = k4 << 2;
            int c = e / NS;          // compiler magic-mul
            int s = e - c * NS;
            floatv4 v;
            v.x = tile[(c << 6) + (((s >> 2) | ((s & 3) << 4)) ^ (c >> 2))];
            if (++s == NS) { s = 0; ++c; }
            v.y = tile[(c << 6) + (((s >> 2) | ((s & 3) << 4)) ^ (c >> 2))];
            if (++s == NS) { s = 0; ++c; }
            v.z = tile[(c << 6) + (((s >> 2) | ((s & 3) << 4)) ^ (c >> 2))];
            if (++s == NS) { s = 0; ++c; }
            v.w = tile[(c << 6) + (((s >> 2) | ((s & 3) << 4)) ^ (c >> 2))];
            __builtin_nontemporal_store(v, (floatv4*)outc + k4);
        }
        __syncthreads();
    }
}

// Fallback (ws too small for transpose): original scalar path on raw feats.
__global__ __launch_bounds__(256) void roi_pool_fb(const float* __restrict__ src,
                                                   const float* __restrict__ boxes,
                                                   const int* __restrict__ ih_p,
                                                   const int* __restrict__ iw_p,
                                                   float* __restrict__ out) {
    __shared__ int4   s_off[NS];
    __shared__ float4 s_wt[NS];
    __shared__ float  tile[NS * 257];

    const int b   = blockIdx.x;
    const int tid = threadIdx.x;

    if (tid < NS) {
        int4 o; float4 w4;
        box_setup(tid, b, boxes, ih_p, iw_p, &o, &w4);
        s_off[tid] = o;
        s_wt[tid]  = w4;
    }
    __syncthreads();

    const size_t outbase = (size_t)b * (CC * NS);
    for (int c0 = 0; c0 < CC; c0 += 256) {
        const int cterm = (c0 + tid) * (HF * WF);
        for (int s = 0; s < NS; ++s) {
            int4   o = s_off[s];
            float4 w = s_wt[s];
            float v = src[o.x + cterm] * w.x + src[o.y + cterm] * w.y +
                      src[o.z + cterm] * w.z + src[o.w + cterm] * w.w;
            tile[s * 257 + tid] = v;
        }
        __syncthreads();
        const size_t ob = outbase + (size_t)c0 * NS;
        for (int k = tid; k < 256 * NS; k += 256) {
            int cl = k / NS;
            int s  = k - cl * NS;
            out[ob + k] = tile[s * 257 + cl];
        }
        __syncthreads();
    }
}

extern "C" void kernel_launch(void* const* d_in, const int* in_sizes, int n_in,
                              void* d_out, int out_size, void* d_ws, size_t ws_size,
                              hipStream_t stream) {
    const float* feats = (const float*)d_in[0];
    const float* boxes = (const float*)d_in[1];
    const int*   ih    = (const int*)d_in[2];
    const int*   iw    = (const int*)d_in[3];
    float*       out   = (float*)d_out;
    const int B = in_sizes[1] / 4;

    const size_t tf_bytes = (size_t)CC * HF * WF * sizeof(float);  // 32 MiB
    const size_t need = tf_bytes + (size_t)B * sizeof(int);
    if (ws_size >= need) {
        float* tf   = (float*)d_ws;
        int*   perm = (int*)((char*)d_ws + tf_bytes);
        dim3 tb(32, 8);
        dim3 tg((HF * WF) / 32, CC / 32);
        transpose_feats<<<tg, tb, 0, stream>>>(feats, tf);
        sort_boxes<<<1, 256, 0, stream>>>(boxes, ih, iw, B, perm);
        roi_pool_v4<<<B, 256, 0, stream>>>(tf, boxes, ih, iw, perm, out);
    } else {
        roi_pool_fb<<<B, 256, 0, stream>>>(feats, boxes, ih, iw, out);
    }
}